// Round 9
// baseline (300.373 us; speedup 1.0000x reference)
//
#include <hip/hip_runtime.h>

typedef __attribute__((ext_vector_type(8))) short short8;
typedef __attribute__((ext_vector_type(4))) float floatx4;

#define N_ROWS 65536
#define K_CB   1024
#define D_DIM  256

// single-term distance (ah*bh): residual terms dropped; error folded into the
// recheck band (R6-R8-proven numerics, absmax 0.0).
#define TAU 4.0e-4f
#define BLINE 520   // shorts per B LDS line (512 data + 8 pad = 1040 B)
#define PRS 260     // floats per staged e-row (256 data + 4 pad; 4-bank stagger)

// ws layout (bytes) — ws_size >= 14 MB proven on this harness
#define OFF_WN     262144    // float[1024]
#define OFF_FIXCNT 266240    // int
#define OFF_HIST   266496    // int[1024]
#define OFF_IDX    270592    // int[65536]
#define OFF_LIST   532736    // int[65536]
#define OFF_PART   794880    // double[4096]
#define OFF_WFRAG  827392    // ushort[32*1024*8] = 512 KB (hi fragments only)
#define OFF_KEYS   1351680   // u64[65536] = 512 KB (fixup argmin keys)
#define OFF_WT     1875968   // float[256*1024] = 1 MB (W transposed [d][k])

// ---- numpy pairwise fp32 sum-of-squares emulation (contract off!) ----
__device__ __forceinline__ float pw128_sq(const float4* p) {
#pragma clang fp contract(off)
    float4 q0 = p[0], q1 = p[1];
    float r0 = q0.x * q0.x, r1 = q0.y * q0.y, r2 = q0.z * q0.z, r3 = q0.w * q0.w;
    float r4 = q1.x * q1.x, r5 = q1.y * q1.y, r6 = q1.z * q1.z, r7 = q1.w * q1.w;
    for (int i = 1; i < 16; ++i) {
        float4 u0 = p[2 * i], u1 = p[2 * i + 1];
        r0 = r0 + u0.x * u0.x; r1 = r1 + u0.y * u0.y;
        r2 = r2 + u0.z * u0.z; r3 = r3 + u0.w * u0.w;
        r4 = r4 + u1.x * u1.x; r5 = r5 + u1.y * u1.y;
        r6 = r6 + u1.z * u1.z; r7 = r7 + u1.w * u1.w;
    }
    return ((r0 + r1) + (r2 + r3)) + ((r4 + r5) + (r6 + r7));
}
__device__ __forceinline__ float rownorm_np(const float* row) {
#pragma clang fp contract(off)
    float s0 = pw128_sq((const float4*)row);
    float s1 = pw128_sq((const float4*)(row + 128));
    return s0 + s1;
}
__device__ __forceinline__ float np_dist(float A, float m, float Ck) {
#pragma clang fp contract(off)
    float Bv = 2.0f * m;
    float t  = A - Bv;
    return t + Ck;
}
__device__ __forceinline__ unsigned short bf16_rne(float x) {
    unsigned u = __float_as_uint(x);
    unsigned r = u + 0x7fff + ((u >> 16) & 1);
    return (unsigned short)(r >> 16);
}
__device__ __forceinline__ unsigned long long dist_key(float d, int idx) {
    unsigned u = __float_as_uint(d);
    unsigned k32 = u ^ (((unsigned)((int)u >> 31)) | 0x80000000u);
    return ((unsigned long long)k32 << 32) | (unsigned)idx;
}

// ---------------- K1: prep — w-norms + wfrag + wT ----------------
__global__ __launch_bounds__(256) void k_prep(
        const float* __restrict__ wg,
        float* __restrict__ wn,
        unsigned short* __restrict__ wfrag, float* __restrict__ wt) {
    __shared__ __align__(16) float es[32 * PRS];
    const int tid = threadIdx.x;
    const int bx  = blockIdx.x;
    if (bx < 4) {
        int row = bx * 256 + tid;
        wn[row] = rownorm_np(wg + (size_t)row * D_DIM);
    } else if (bx < 132) {
        // ---- wfrag: bf16-hi fragments only, layout [kc][col][8] ----
        int t = (bx - 4) * 256 + tid;        // 0..32767
        int col = t >> 5, kc = t & 31;
        const float4* src = (const float4*)(wg + (size_t)col * D_DIM + kc * 8);
        float4 v0 = src[0], v1 = src[1];
        const float a[8] = {v0.x, v0.y, v0.z, v0.w, v1.x, v1.y, v1.z, v1.w};
        short8 h;
        #pragma unroll
        for (int i = 0; i < 8; ++i) h[i] = (short)bf16_rne(a[i]);
        *(short8*)(wfrag + ((size_t)kc * 1024 + col) * 8) = h;
    } else {
        // ---- wT: float transpose [d][k], 32 codes per block via LDS ----
        float (*tw)[PRS] = (float(*)[PRS])es;   // [32][260]
        const int cb = bx - 132;                // 0..31
        const int c0 = cb * 32;
        #pragma unroll
        for (int it = 0; it < 8; ++it) {
            int idx = it * 256 + tid;           // float4 index
            int code = idx >> 6, f4 = idx & 63;
            *(float4*)&tw[code][f4 * 4] =
                *(const float4*)(wg + (size_t)(c0 + code) * D_DIM + f4 * 4);
        }
        __syncthreads();
        const int j = tid & 31, dg = tid >> 5;  // dg 0..7
        #pragma unroll
        for (int dd = 0; dd < 32; ++dd) {
            int d = dd * 8 + dg;
            wt[(size_t)d * K_CB + c0 + j] = tw[j][d];
        }
    }
}

// ---------------- K2: MFMA distance — 2-wave blocks, 4 blocks/CU ----------------
// grid(1024): block = 128 threads (2 waves x 32 rows); 16 col-phases of 64 codes.
// R8 lesson: the kernel was pinned by grid=512 -> 2 blocks/CU in 4-wave
// barrier lockstep (occ 20%, 3x stall gap over pipe floor). Fix: 2-wave
// blocks + single-buffer LDS (33.3+4 KB) -> 4 blocks/CU, 8 waves/CU in 4
// INDEPENDENT barrier domains; one block's stage/barrier overlaps another's
// compute. Plain launch_bounds(128): explicit min-waves shrinks the VGPR
// budget and spills (R4 lesson).
__global__ __launch_bounds__(128) void k_dist(
        const float* __restrict__ eg, const unsigned short* __restrict__ wfrag,
        const float* __restrict__ wn,
        int* __restrict__ idx_ws, int* __restrict__ fixlist, int* __restrict__ fixcnt) {
    __shared__ __align__(16) unsigned short Bs[32 * BLINE];   // 33.28 KB
    __shared__ float wnS[K_CB];                               // 4 KB
    const int tid  = threadIdx.x;
    const int lane = tid & 63;
    const int wv   = tid >> 6;           // 0,1
    const int q    = lane >> 4;
    const int m15  = lane & 15;
    const int waveRow = blockIdx.x * 64 + wv * 32;

    // ---- wn -> LDS once (published by first prologue barrier) ----
    #pragma unroll
    for (int i = 0; i < 8; ++i) wnS[tid + i * 128] = wn[tid + i * 128];

    // ---- A fragments via coalesced LDS round-trip (Bs reused as [32][PRS] f32) ----
    float* ef = (float*)&Bs[0];          // 32*260*4 = 33280 B = sizeof(Bs)
    short8 afh0[8], afh1[8];
    #pragma unroll
    for (int round = 0; round < 2; ++round) {
        // both waves stage this round's 32 rows (16 coalesced 1KB lines each)
        #pragma unroll
        for (int t = 0; t < 16; ++t) {
            int line = wv * 16 + t;
            const float* src = eg + (size_t)(blockIdx.x * 64 + round * 32 + line) * D_DIM + lane * 4;
            __builtin_amdgcn_global_load_lds(
                (const __attribute__((address_space(1))) unsigned int*)src,
                (__attribute__((address_space(3))) unsigned int*)&ef[line * PRS],
                16, 0, 0);
        }
        __syncthreads();   // drain stage (also publishes wnS on round 0)
        if (wv == round) {
            #pragma unroll
            for (int mt = 0; mt < 2; ++mt) {
                const float* rowp = &ef[(mt * 16 + m15) * PRS + q * 8];
                #pragma unroll
                for (int win = 0; win < 8; ++win) {
                    float4 x0 = *(const float4*)(rowp + win * 32);
                    float4 x1 = *(const float4*)(rowp + win * 32 + 4);
                    const float a[8] = {x0.x, x0.y, x0.z, x0.w, x1.x, x1.y, x1.z, x1.w};
                    short8 h;
                    #pragma unroll
                    for (int i = 0; i < 8; ++i) h[i] = (short)bf16_rne(a[i]);
                    if (mt == 0) afh0[win] = h; else afh1[win] = h;
                }
            }
        }
        __syncthreads();   // fragments read; ef region free for reuse
    }

    float best[8], sec[8];
    int bidx[8];
    #pragma unroll
    for (int s = 0; s < 8; ++s) { best[s] = 3.4e38f; sec[s] = 3.4e38f; bidx[s] = 0; }

    for (int cb = 0; cb < 16; ++cb) {
        // ---- stage this phase's B tile: 32 lines, 16 per wave ----
        #pragma unroll
        for (int t = 0; t < 16; ++t) {
            int L = wv * 16 + t;   // = kc 0..31
            const unsigned short* src = wfrag + ((size_t)L * 1024 + cb * 64) * 8 + lane * 8;
            __builtin_amdgcn_global_load_lds(
                (const __attribute__((address_space(1))) unsigned int*)src,
                (__attribute__((address_space(3))) unsigned int*)&Bs[L * BLINE],
                16, 0, 0);
        }
        __syncthreads();   // vmcnt(0) drain before barrier

        // ---- compute: win outer -> 8 independent acc chains ----
        floatx4 acc[2][4];
        #pragma unroll
        for (int mt = 0; mt < 2; ++mt)
            #pragma unroll
            for (int nt = 0; nt < 4; ++nt)
                acc[mt][nt] = (floatx4){0.f, 0.f, 0.f, 0.f};
        #pragma unroll
        for (int win = 0; win < 8; ++win) {
            int kc = win * 4 + q;
            #pragma unroll
            for (int nt = 0; nt < 4; ++nt) {
                short8 bfh = *(short8*)&Bs[kc * BLINE + (nt * 16 + m15) * 8];
                acc[0][nt] = __builtin_amdgcn_mfma_f32_16x16x32_bf16(afh0[win], bfh, acc[0][nt], 0, 0, 0);
                acc[1][nt] = __builtin_amdgcn_mfma_f32_16x16x32_bf16(afh1[win], bfh, acc[1][nt], 0, 0, 0);
            }
        }
        // ---- fold into running top-2 (cols ascend with cb,nt -> first-min kept) ----
        #pragma unroll
        for (int nt = 0; nt < 4; ++nt) {
            int col = cb * 64 + nt * 16 + m15;
            float Ck = wnS[col];
            #pragma unroll
            for (int reg = 0; reg < 4; ++reg) {
                float d0 = __builtin_fmaf(-2.0f, acc[0][nt][reg], Ck);
                bool lt0 = d0 < best[reg];
                sec[reg]  = __builtin_amdgcn_fmed3f(d0, best[reg], sec[reg]);
                best[reg] = fminf(d0, best[reg]);
                bidx[reg] = lt0 ? col : bidx[reg];
                float d1 = __builtin_fmaf(-2.0f, acc[1][nt][reg], Ck);
                int s1 = 4 + reg;
                bool lt1 = d1 < best[s1];
                sec[s1]  = __builtin_amdgcn_fmed3f(d1, best[s1], sec[s1]);
                best[s1] = fminf(d1, best[s1]);
                bidx[s1] = lt1 ? col : bidx[s1];
            }
        }
        __syncthreads();   // Bs free for next phase
    }

    // butterfly top-2 merge across the 16 m15 lanes (rows live per (q,mt,reg))
    #pragma unroll
    for (int s = 0; s < 8; ++s) {
        float b = best[s], se = sec[s];
        int ix = bidx[s];
        #pragma unroll
        for (int m = 1; m < 16; m <<= 1) {
            float bo = __shfl_xor(b, m, 64);
            float so = __shfl_xor(se, m, 64);
            int   io = __shfl_xor(ix, m, 64);
            float ns = fminf(fminf(se, so), fmaxf(b, bo));
            if (bo < b || (bo == b && io < ix)) { b = bo; ix = io; }
            se = ns;
        }
        if (m15 == 0) {
            int row = waveRow + (s >> 2) * 16 + q * 4 + (s & 3);
            idx_ws[row] = ix;
            if (se - b < TAU) {
                int p = atomicAdd(fixcnt, 1);
                fixlist[p] = row;
            }
        }
    }
}

// ---------------- K3: recheck — fp32-chain sweep + fp64 verify of top-2 ----------------
// np_dist quantizes distances to a 3.05e-5 grid (d~256, ulp 2^-15); fp32-chain
// m error ~1e-8 can never displace a code by a full grid step, so the true
// argmin is always within each wave's approx top-2. fp64-verify those two
// (wave-parallel), atomicMin the verified key.
#define FG_ROWS 8
__global__ __launch_bounds__(256) void k_fixup(
        const float* __restrict__ eg, const float* __restrict__ wg,
        const float* __restrict__ wt, const float* __restrict__ wnorm,
        const int* __restrict__ fixlist, const int* __restrict__ fixcnt,
        unsigned long long* __restrict__ keys) {
    __shared__ __align__(16) float xs[FG_ROWS][D_DIM];   // 8 KB
    __shared__ float AnS[FG_ROWS];
    const int tid  = threadIdx.x;
    const int lane = tid & 63;
    const int cnt = *fixcnt;
    if (cnt == 0) return;
    const int ngroups = (cnt + FG_ROWS - 1) / FG_ROWS;
    const int ntiles  = ngroups * 2;
    const int rowg = tid >> 7;               // 0,1 -> rows 4*rowg..4*rowg+3
    const int cg   = tid & 127;              // code group (4 codes each)
    for (int t = blockIdx.x; t < ntiles; t += gridDim.x) {
        const int g     = t >> 1;
        const int chunk = t & 1;
        __syncthreads();   // xs/AnS reuse guard across grid-stride tiles
        int rows[FG_ROWS];
        #pragma unroll
        for (int i = 0; i < FG_ROWS; ++i) {
            int j = g * FG_ROWS + i;
            rows[i] = fixlist[j < cnt ? j : cnt - 1];
        }
        #pragma unroll
        for (int i = 0; i < FG_ROWS; ++i)
            xs[i][tid] = eg[(size_t)rows[i] * D_DIM + tid];
        __syncthreads();

        // ---- row norms from LDS copy (numpy-pairwise-exact) ----
        if (tid < 16) {
            int row = tid >> 1, half = tid & 1;
            float sN = pw128_sq((const float4*)&xs[row][half * 128]);
            float so = __shfl_xor(sN, 1, 64);
            if (half == 0) AnS[row] = sN + so;
        }

        const int c0 = chunk * 512 + cg * 4;
        float Cw[4];
        #pragma unroll
        for (int c = 0; c < 4; ++c) Cw[c] = wnorm[c0 + c];

        float s[4][4];
        #pragma unroll
        for (int r = 0; r < 4; ++r)
            #pragma unroll
            for (int c = 0; c < 4; ++c) s[r][c] = 0.f;

        #pragma unroll 2
        for (int d = 0; d < D_DIM; d += 2) {
            float4 wa = *(const float4*)(wt + (size_t)d * K_CB + c0);
            float4 wb = *(const float4*)(wt + (size_t)(d + 1) * K_CB + c0);
            #pragma unroll
            for (int r = 0; r < 4; ++r) {
                float2 e2 = *(const float2*)&xs[rowg * 4 + r][d];
                s[r][0] += e2.x * wa.x + e2.y * wb.x;
                s[r][1] += e2.x * wa.y + e2.y * wb.y;
                s[r][2] += e2.x * wa.z + e2.y * wb.z;
                s[r][3] += e2.x * wa.w + e2.y * wb.w;
            }
        }
        __syncthreads();   // AnS ready for all threads

        #pragma unroll
        for (int r = 0; r < 4; ++r) {
            const int R = rowg * 4 + r;
            float An = AnS[R];
            unsigned long long kb = 0xFFFFFFFFFFFFFFFFull, ks = 0xFFFFFFFFFFFFFFFFull;
            #pragma unroll
            for (int c = 0; c < 4; ++c) {
                float dq = np_dist(An, s[r][c], Cw[c]);
                unsigned long long kk = dist_key(dq, c0 + c);
                if (kk < kb) { ks = kb; kb = kk; }
                else if (kk < ks) { ks = kk; }
            }
            #pragma unroll
            for (int m = 1; m < 64; m <<= 1) {
                unsigned long long ko = __shfl_xor(kb, m, 64);
                unsigned long long so = __shfl_xor(ks, m, 64);
                if (ko < kb) { ks = (so < kb) ? so : kb; kb = ko; }
                else         { ks = (ko < ks) ? ko : ks; }
            }
            int cand = (int)((lane < 32 ? kb : ks) & 0xFFFFFFFFull);
            const float* wrow = wg + (size_t)cand * D_DIM + (lane & 31) * 8;
            const float* erow = &xs[R][(lane & 31) * 8];
            double sm = 0.0;
            #pragma unroll
            for (int jj = 0; jj < 8; ++jj)
                sm += (double)erow[jj] * (double)wrow[jj];
            #pragma unroll
            for (int m = 1; m < 32; m <<= 1) sm += __shfl_xor(sm, m, 64);
            double smo = __shfl_xor(sm, 32, 64);
            if (lane == 0) {
                int i0 = (int)(kb & 0xFFFFFFFFull);
                int i1 = (int)(ks & 0xFFFFFFFFull);
                float d0 = np_dist(An, (float)sm,  wnorm[i0]);
                float d1 = np_dist(An, (float)smo, wnorm[i1]);
                unsigned long long k0 = dist_key(d0, i0);
                unsigned long long k1 = dist_key(d1, i1);
                unsigned long long kf = k0 < k1 ? k0 : k1;
                int j = g * FG_ROWS + R;
                if (j < cnt) atomicMin(&keys[j], kf);
            }
        }
    }
}

// ---------------- K3b: scatter fixup winners back into idx_ws ----------------
__global__ void k_fixscatter(const int* __restrict__ fixlist, const int* __restrict__ fixcnt,
                             const unsigned long long* __restrict__ keys,
                             int* __restrict__ idx_ws) {
    const int cnt = *fixcnt;
    for (int j = blockIdx.x * blockDim.x + threadIdx.x; j < cnt;
         j += gridDim.x * blockDim.x)
        idx_ws[fixlist[j]] = (int)(keys[j] & 0xFFFFFFFFull);
}

// ---------------- K4: gather + STE + loss partials + histogram (float4 vectorized) ----------------
__global__ void k_final(const float* __restrict__ eg, const float* __restrict__ wg,
                        const int* __restrict__ idx_ws, float* __restrict__ qout,
                        float* __restrict__ iout, int* __restrict__ hist,
                        double* __restrict__ partials) {
    const int tid  = threadIdx.x;
    const int sub  = tid >> 6;      // 0..3: row within quad
    const int lane = tid & 63;      // float4 column
    const int rowBase = blockIdx.x * 16;
    double acc = 0.0;
    #pragma unroll
    for (int g = 0; g < 4; ++g) {
        int row = rowBase + g * 4 + sub;
        int k = idx_ws[row];
        float4 ev = ((const float4*)(eg + (size_t)row * D_DIM))[lane];
        float4 wv = ((const float4*)(wg + (size_t)k   * D_DIM))[lane];
        float dx = wv.x - ev.x, dy = wv.y - ev.y, dz = wv.z - ev.z, dw = wv.w - ev.w;
        float4 qv = {ev.x + dx, ev.y + dy, ev.z + dz, ev.w + dw};
        ((float4*)(qout + (size_t)row * D_DIM))[lane] = qv;
        acc += (double)(dx * dx) + (double)(dy * dy)
             + (double)(dz * dz) + (double)(dw * dw);
        if (lane == 0) {
            iout[row] = (float)k;
            atomicAdd(&hist[k], 1);
        }
    }
    __shared__ double red[256];
    red[tid] = acc;
    __syncthreads();
    for (int st = 128; st > 0; st >>= 1) {
        if (tid < st) red[tid] += red[tid + st];
        __syncthreads();
    }
    if (tid == 0) partials[blockIdx.x] = red[0];
}

// ---------------- K5: scalars ----------------
__global__ void k_scalars(const int* __restrict__ hist, const double* __restrict__ partials,
                          float* __restrict__ sout) {
    const int tid = threadIdx.x;
    double s = 0.0;
    for (int j = tid; j < N_ROWS / 16; j += 256) s += partials[j];
    int m = 0;
    for (int j = tid; j < K_CB; j += 256) m = max(m, hist[j]);
    __shared__ double rs[256];
    __shared__ int    rm[256];
    rs[tid] = s; rm[tid] = m;
    __syncthreads();
    for (int st = 128; st > 0; st >>= 1) {
        if (tid < st) { rs[tid] += rs[tid + st]; rm[tid] = max(rm[tid], rm[tid + st]); }
        __syncthreads();
    }
    if (tid == 0) {
        sout[0] = (float)(rs[0] / (double)((size_t)N_ROWS * D_DIM));
        sout[1] = (float)rm[0] / 65536.0f;
    }
}

extern "C" void kernel_launch(void* const* d_in, const int* in_sizes, int n_in,
                              void* d_out, int out_size, void* d_ws, size_t ws_size,
                              hipStream_t stream) {
    const float* e = (const float*)d_in[0];
    const float* w = (const float*)d_in[1];
    float* out  = (float*)d_out;
    float* qout = out;
    float* iout = out + (size_t)N_ROWS * D_DIM;
    float* sout = iout + N_ROWS;

    char* ws = (char*)d_ws;
    float*  wn       = (float*) (ws + OFF_WN);
    int*    fixcnt   = (int*)   (ws + OFF_FIXCNT);
    int*    hist     = (int*)   (ws + OFF_HIST);
    int*    idxp     = (int*)   (ws + OFF_IDX);
    int*    list     = (int*)   (ws + OFF_LIST);
    double* partials = (double*)(ws + OFF_PART);
    unsigned short* wfrag = (unsigned short*)(ws + OFF_WFRAG);
    unsigned long long* keys = (unsigned long long*)(ws + OFF_KEYS);
    float*  wt       = (float*) (ws + OFF_WT);

    hipMemsetAsync(ws + OFF_FIXCNT, 0, 4352, stream);        // fixcnt + hist
    hipMemsetAsync(ws + OFF_KEYS, 0xFF, 524288, stream);     // keys = u64 max

    hipLaunchKernelGGL(k_prep,       dim3(164),         dim3(256), 0, stream, w, wn, wfrag, wt);
    hipLaunchKernelGGL(k_dist,       dim3(1024),        dim3(128), 0, stream, e, wfrag, wn, idxp, list, fixcnt);
    hipLaunchKernelGGL(k_fixup,      dim3(2048),        dim3(256), 0, stream, e, w, wt, wn, list, fixcnt, keys);
    hipLaunchKernelGGL(k_fixscatter, dim3(64),          dim3(256), 0, stream, list, fixcnt, keys, idxp);
    hipLaunchKernelGGL(k_final,      dim3(N_ROWS / 16), dim3(256), 0, stream, e, w, idxp, qout, iout, hist, partials);
    hipLaunchKernelGGL(k_scalars,    dim3(1),           dim3(256), 0, stream, hist, partials, sout);
}